// Round 8
// baseline (167.418 us; speedup 1.0000x reference)
//
#include <hip/hip_runtime.h>
#include <hip/hip_bf16.h>
#include <math.h>

// Batch-hard triplet loss, B=8192, D=128, fp32 in. Fully fused:
//   K1 init: zero pmkey/nmkey/ticket (ws is 0xAA-poisoned).
//   K2 tile: fp32->bf16 in-register staging (XOR swizzle, R5-validated),
//            inline colterm (shuffle-reduce during B staging), inline rowterm
//            (blockIdx.y==0 during A staging), A-frag register hoist,
//            4x4 mfma_f32_16x16x32_bf16, dist^2-space masked max/min,
//            device-scope atomicMax on monotone-encoded uints,
//            ticket -> last block finalizes (hinge + anchor mean) -> out.
// dist^2[i,j] = rowterm[i] + colterm[j] - 2*dot;  sqrt & max/min commute.

#define DDIM   128
#define SPLITS 8
#define MARGIN 0.2f
#define EPS    1e-6f
#define SENT   1e30f

typedef unsigned short ushort_t;
typedef __attribute__((ext_vector_type(8))) short short8;
typedef __attribute__((ext_vector_type(8))) unsigned short ushort8;
typedef __attribute__((ext_vector_type(4))) float f32x4;

__device__ __forceinline__ ushort_t f2bf(float f) {   // fp32 -> bf16 RNE
    unsigned int u = __float_as_uint(f);
    u = (u + 0x7FFFu + ((u >> 16) & 1u)) >> 16;
    return (ushort_t)u;
}

// monotone float<->uint encoding: enc(a) < enc(b) iff a < b (total order)
__device__ __forceinline__ unsigned enc(float f) {
    unsigned b = __float_as_uint(f);
    return (b & 0x80000000u) ? ~b : (b | 0x80000000u);
}
__device__ __forceinline__ float dec(unsigned k) {
    unsigned b = (k & 0x80000000u) ? (k & 0x7FFFFFFFu) : ~k;
    return __uint_as_float(b);
}

// ---- kernel 1: zero the atomic-destination arrays (ws is poisoned) ------
__global__ void init_kernel(unsigned* __restrict__ pmkey, unsigned* __restrict__ nmkey,
                            int* __restrict__ ticket, int B) {
    int i = blockIdx.x * blockDim.x + threadIdx.x;
    if (i < B) { pmkey[i] = 0u; nmkey[i] = 0u; }   // 0 = smallest key
    if (i == 0) *ticket = 0;
}

// ---- kernel 2: fully fused tile + reductions ----------------------------
// grid (B/128, SPLITS), block 256 = 4 waves; 128x128 tile, K=128 in LDS.
__global__ __launch_bounds__(256, 2)
void tile_kernel(const float* __restrict__ e1, const float* __restrict__ e2,
                 const int* __restrict__ target,
                 float* __restrict__ rowterm,
                 unsigned* __restrict__ pmkey, unsigned* __restrict__ nmkey,
                 int* __restrict__ ticket, float* __restrict__ out, int B) {
    __shared__ __align__(16) ushort_t As[128 * DDIM];   // 32 KB
    __shared__ __align__(16) ushort_t Bs[128 * DDIM];   // 32 KB
    __shared__ float ctP[128], ctN[128];                // per-tile col terms
    __shared__ int lastSh;

    const int tid = threadIdx.x;
    const int w   = tid >> 6;
    const int l   = tid & 63;
    const int lq  = l >> 4;
    const int lm  = l & 15;
    const int row0 = blockIdx.x * 128;
    const int colSpan = B / SPLITS;                  // 1024
    const int col0 = blockIdx.y * colSpan;
    const int nTiles = colSpan / 128;                // 8
    const int nBlocks = gridDim.x * gridDim.y;       // 512

    // ---- stage A (+ rowterm if blockIdx.y==0) --------------------------
    {
        const float* g = e1 + (size_t)row0 * DDIM;
        const bool doStats = (blockIdx.y == 0);
        #pragma unroll
        for (int it = 0; it < 8; ++it) {
            int idx = it * 256 + tid;
            int r   = idx >> 4;
            int c8  = idx & 15;
            const float* src = g + (size_t)r * DDIM + c8 * 8;
            float4 v0 = *(const float4*)src;
            float4 v1 = *(const float4*)(src + 4);
            ushort8 o;
            o[0]=f2bf(v0.x); o[1]=f2bf(v0.y); o[2]=f2bf(v0.z); o[3]=f2bf(v0.w);
            o[4]=f2bf(v1.x); o[5]=f2bf(v1.y); o[6]=f2bf(v1.z); o[7]=f2bf(v1.w);
            *(ushort8*)(As + r * DDIM + ((c8 ^ (r & 15)) << 3)) = o;
            if (doStats) {
                float s8 = (v0.x+v0.y)+(v0.z+v0.w)+(v1.x+v1.y)+(v1.z+v1.w);
                float q8 = v0.x*v0.x+v0.y*v0.y+v0.z*v0.z+v0.w*v0.w
                         + v1.x*v1.x+v1.y*v1.y+v1.z*v1.z+v1.w*v1.w;
                #pragma unroll
                for (int m = 1; m < 16; m <<= 1) {
                    s8 += __shfl_xor(s8, m, 64);
                    q8 += __shfl_xor(q8, m, 64);
                }
                if (lm == 0) {   // device-coherent store (read cross-XCD later)
                    float rt = q8 + 2.f * EPS * s8 + (float)DDIM * EPS * EPS;
                    atomicExch(&rowterm[row0 + r], rt);
                }
            }
        }
    }

    const int wr = (w >> 1) * 64;
    const int wc = (w & 1) * 64;

    // ---- stage B tile t: convert + colterm into LDS --------------------
    auto stageB = [&](int t) {
        const float* g = e2 + (size_t)(col0 + t * 128) * DDIM;
        const int* tg0 = target + col0 + t * 128;
        #pragma unroll
        for (int it = 0; it < 8; ++it) {
            int idx = it * 256 + tid;
            int r   = idx >> 4;
            int c8  = idx & 15;
            const float* src = g + (size_t)r * DDIM + c8 * 8;
            float4 v0 = *(const float4*)src;
            float4 v1 = *(const float4*)(src + 4);
            ushort8 o;
            o[0]=f2bf(v0.x); o[1]=f2bf(v0.y); o[2]=f2bf(v0.z); o[3]=f2bf(v0.w);
            o[4]=f2bf(v1.x); o[5]=f2bf(v1.y); o[6]=f2bf(v1.z); o[7]=f2bf(v1.w);
            *(ushort8*)(Bs + r * DDIM + ((c8 ^ (r & 15)) << 3)) = o;
            float s8 = (v0.x+v0.y)+(v0.z+v0.w)+(v1.x+v1.y)+(v1.z+v1.w);
            float q8 = v0.x*v0.x+v0.y*v0.y+v0.z*v0.z+v0.w*v0.w
                     + v1.x*v1.x+v1.y*v1.y+v1.z*v1.z+v1.w*v1.w;
            #pragma unroll
            for (int m = 1; m < 16; m <<= 1) {
                s8 += __shfl_xor(s8, m, 64);
                q8 += __shfl_xor(q8, m, 64);
            }
            if (lm == 0) {
                float ct = q8 - 2.f * EPS * s8;
                int tg = tg0[r];
                ctP[r] = (tg == 1) ? ct : -SENT;
                ctN[r] = (tg == 0) ? ct :  SENT;
            }
        }
    };

    stageB(0);
    __syncthreads();                 // As, Bs(0), ctP/ctN visible

    // hoist A fragments: rows wr + i*16 + lm; chunk (lq + kk/8) ^ lm
    const ushort_t* aRow = As + (wr + lm) * DDIM;
    const ushort_t* bRow = Bs + (wc + lm) * DDIM;
    short8 afr[4][4];
    #pragma unroll
    for (int i = 0; i < 4; ++i)
        #pragma unroll
        for (int k4 = 0; k4 < 4; ++k4)
            afr[i][k4] = *(const short8*)(aRow + i * 16 * DDIM
                                          + (((lq + k4 * 4) ^ lm) << 3));

    float pm[4][4], nm[4][4];        // [i][r]: local row = wr + i*16 + lq*4 + r
    #pragma unroll
    for (int i = 0; i < 4; ++i)
        #pragma unroll
        for (int r = 0; r < 4; ++r) { pm[i][r] = -SENT; nm[i][r] = SENT; }

    for (int t = 0; t < nTiles; ++t) {
        f32x4 acc[4][4];
        #pragma unroll
        for (int i = 0; i < 4; ++i)
            #pragma unroll
            for (int j = 0; j < 4; ++j)
                acc[i][j] = (f32x4){0.f, 0.f, 0.f, 0.f};

        #pragma unroll
        for (int kk = 0; kk < DDIM; kk += 32) {
            const int k4 = kk >> 5;
            const int co = (((lq + (kk >> 3)) ^ lm) << 3);
            short8 bf[4];
            #pragma unroll
            for (int j = 0; j < 4; ++j)
                bf[j] = *(const short8*)(bRow + j * 16 * DDIM + co);
            #pragma unroll
            for (int i = 0; i < 4; ++i)
                #pragma unroll
                for (int j = 0; j < 4; ++j)
                    acc[i][j] = __builtin_amdgcn_mfma_f32_16x16x32_bf16(
                                    afr[i][k4], bf[j], acc[i][j], 0, 0, 0);
        }

        // branchless epilogue in dist^2 space (col terms from LDS)
        #pragma unroll
        for (int j = 0; j < 4; ++j) {
            int lc = wc + j * 16 + lm;          // C/D: col = lane&15
            float cp = ctP[lc];
            float cn = ctN[lc];
            #pragma unroll
            for (int i = 0; i < 4; ++i)
                #pragma unroll
                for (int r = 0; r < 4; ++r) {
                    float d = acc[i][j][r];
                    pm[i][r] = fmaxf(pm[i][r], fmaf(-2.f, d, cp));
                    nm[i][r] = fminf(nm[i][r], fmaf(-2.f, d, cn));
                }
        }

        if (t + 1 < nTiles) {
            __syncthreads();         // readers of Bs/ctP/ctN done
            stageB(t + 1);
            __syncthreads();         // new tile visible
        }
    }

    // intra-wave: reduce across the 16 column-lanes
    #pragma unroll
    for (int m = 1; m < 16; m <<= 1) {
        #pragma unroll
        for (int i = 0; i < 4; ++i)
            #pragma unroll
            for (int r = 0; r < 4; ++r) {
                pm[i][r] = fmaxf(pm[i][r], __shfl_xor(pm[i][r], m, 64));
                nm[i][r] = fminf(nm[i][r], __shfl_xor(nm[i][r], m, 64));
            }
    }

    // cross-wave combine (waves 2h / 2h+1 share rows), then global atomics
    __syncthreads();
    float* smP = (float*)As;               // A lives in registers now
    float* smN = smP + 128;
    if ((w & 1) == 1 && lm == 0) {
        #pragma unroll
        for (int i = 0; i < 4; ++i)
            #pragma unroll
            for (int r = 0; r < 4; ++r) {
                int lr = wr + i * 16 + lq * 4 + r;
                smP[lr] = pm[i][r];
                smN[lr] = nm[i][r];
            }
    }
    __syncthreads();
    if ((w & 1) == 0 && lm == 0) {
        #pragma unroll
        for (int i = 0; i < 4; ++i)
            #pragma unroll
            for (int r = 0; r < 4; ++r) {
                int lr  = wr + i * 16 + lq * 4 + r;   // C/D: row = quad*4+reg
                int row = row0 + lr;
                float p = fmaxf(pm[i][r], smP[lr]);
                float n = fminf(nm[i][r], smN[lr]);
                atomicMax(&pmkey[row], enc(p));
                atomicMax(&nmkey[row], enc(-n));      // min via max of -n
            }
    }

    // ---- completion ticket; last block finalizes ------------------------
    __threadfence();                 // make rowterm/atomics device-visible
    __syncthreads();
    if (tid == 0) {
        int done = atomicAdd(ticket, 1);
        lastSh = (done == nBlocks - 1);
    }
    __syncthreads();
    if (lastSh) {
        __threadfence();             // acquire side
        float s = 0.f, c = 0.f;
        for (int row = tid; row < B; row += 256) {
            unsigned kp = __hip_atomic_load(&pmkey[row], __ATOMIC_RELAXED,
                                            __HIP_MEMORY_SCOPE_AGENT);
            unsigned kn = __hip_atomic_load(&nmkey[row], __ATOMIC_RELAXED,
                                            __HIP_MEMORY_SCOPE_AGENT);
            float rt = __hip_atomic_load(&rowterm[row], __ATOMIC_RELAXED,
                                         __HIP_MEMORY_SCOPE_AGENT);
            float pmv = dec(kp);
            float nmv = -dec(kn);
            float dp = sqrtf(fmaxf(rt + pmv, 0.f));
            float dn = sqrtf(fmaxf(rt + nmv, 0.f));
            if (target[row] == 1) {
                s += fmaxf(dp - dn + MARGIN, 0.f);
                c += 1.f;
            }
        }
        #pragma unroll
        for (int off = 32; off > 0; off >>= 1) {
            s += __shfl_down(s, off, 64);
            c += __shfl_down(c, off, 64);
        }
        if (l == 0) { ctP[w] = s; ctN[w] = c; }
        __syncthreads();
        if (tid == 0)
            out[0] = (ctP[0] + ctP[1] + ctP[2] + ctP[3])
                   / (ctN[0] + ctN[1] + ctN[2] + ctN[3]);
    }
}

extern "C" void kernel_launch(void* const* d_in, const int* in_sizes, int n_in,
                              void* d_out, int out_size, void* d_ws, size_t ws_size,
                              hipStream_t stream) {
    const float* e1     = (const float*)d_in[0];
    const float* e2     = (const float*)d_in[1];
    const int*   target = (const int*)d_in[2];
    float* out = (float*)d_out;
    const int B = in_sizes[2];                       // 8192

    // ws layout: rowterm[B] | pmkey[B] | nmkey[B] | ticket  (~96 KB)
    char* p = (char*)d_ws;
    float*    rowterm = (float*)p;    p += (size_t)B * 4;
    unsigned* pmkey   = (unsigned*)p; p += (size_t)B * 4;
    unsigned* nmkey   = (unsigned*)p; p += (size_t)B * 4;
    int*      ticket  = (int*)p;

    init_kernel<<<(B + 255) / 256, 256, 0, stream>>>(pmkey, nmkey, ticket, B);

    dim3 grid(B / 128, SPLITS);      // 512 blocks = 2/CU (66.5 KB LDS)
    tile_kernel<<<grid, 256, 0, stream>>>(e1, e2, target, rowterm,
                                          pmkey, nmkey, ticket, out, B);
}

// Round 9
// 92.093 us; speedup vs baseline: 1.8179x; 1.8179x over previous
//
#include <hip/hip_runtime.h>
#include <hip/hip_bf16.h>
#include <math.h>

// Batch-hard triplet loss, B=8192, D=128, fp32 in.
// dist^2[i,j] = rowterm[i] + colterm[j] - 2*dot(e1[i], e2[j])
// sqrt & max/min commute -> track max/min of (colterm - 2*dot); dot on bf16
// matrix cores. Target folded into cpos/cneg (finite +-1e30 sentinels).
//
// R9 vs R7: single-barrier software-pipelined K-loop.
//  - A tile never touches LDS: each lane loads its 16 b128 fragments from
//    e1b global once (L2-hit) -> kills A staging + one barrier.
//  - B double-buffered in LDS via global_load_lds w=16 (padded 1056B-pitch
//    chunks, conflict-free, R6/R7-validated): DMA for t+1 issues at start of
//    iteration t; the single end-of-iteration barrier's vmcnt(0) drain has a
//    full compute phase (~2500 cyc) of slack over the ~1200 cyc L2 fill.
//  - R8's fused shuffle-stats regression reverted (prep/reduce kernels back).

#define DDIM   128
#define SPLITS 8
#define MARGIN 0.2f
#define EPS    1e-6f
#define SENT   1e30f

#define CHUNK_PITCH 1056           // 1024 B data + 32 B pad
#define WAVE_SPAN   (8 * CHUNK_PITCH)     // 8 chunks (32 rows) per wave
#define TILE_BYTES  (4 * WAVE_SPAN)       // 33792 B per 128x128 bf16 tile

typedef unsigned short ushort_t;
typedef __attribute__((ext_vector_type(8))) short short8;
typedef __attribute__((ext_vector_type(4))) float f32x4;

__device__ __forceinline__ ushort_t f2bf(float f) {   // fp32 -> bf16 RNE
    unsigned int u = __float_as_uint(f);
    u = (u + 0x7FFFu + ((u >> 16) & 1u)) >> 16;
    return (ushort_t)u;
}

__device__ __forceinline__ void g2lds16(const ushort_t* g, void* lds) {
    // wave-uniform lds base; lane i's 16 B land at lds + i*16
    __builtin_amdgcn_global_load_lds(
        (const __attribute__((address_space(1))) unsigned int*)g,
        (__attribute__((address_space(3))) unsigned int*)lds,
        16, 0, 0);
}

// ---- kernel 1: bf16 convert + exact fp32 row stats + zero reduce state ----
__global__ void prep_kernel(const float* __restrict__ e1, const float* __restrict__ e2,
                            const int* __restrict__ target,
                            ushort_t* __restrict__ e1b, ushort_t* __restrict__ e2b,
                            float* __restrict__ rowterm,
                            float* __restrict__ cpos, float* __restrict__ cneg,
                            float* __restrict__ redsum, int* __restrict__ ticket, int B) {
    if (blockIdx.x == 0 && threadIdx.x == 0) {
        redsum[0] = 0.f; redsum[1] = 0.f; *ticket = 0;
    }
    int w    = (blockIdx.x * blockDim.x + threadIdx.x) >> 6;
    int lane = threadIdx.x & 63;
    if (w >= 2 * B) return;
    bool first = (w < B);
    int r = first ? w : w - B;
    const float* src = (first ? e1 : e2) + (size_t)r * DDIM;
    float2 v = *(const float2*)(src + lane * 2);
    ushort_t* dst = (first ? e1b : e2b) + (size_t)r * DDIM;
    ushort2 o; o.x = f2bf(v.x); o.y = f2bf(v.y);
    *(ushort2*)(dst + lane * 2) = o;
    float s = v.x + v.y;
    float n = v.x * v.x + v.y * v.y;
    #pragma unroll
    for (int off = 32; off > 0; off >>= 1) {
        s += __shfl_down(s, off, 64);
        n += __shfl_down(n, off, 64);
    }
    if (lane == 0) {
        if (first) {
            rowterm[r] = n + 2.f * EPS * s + (float)DDIM * EPS * EPS;
        } else {
            float ct = n - 2.f * EPS * s;
            int tg = target[r];
            cpos[r] = (tg == 1) ? ct : -SENT;
            cneg[r] = (tg == 0) ? ct :  SENT;
        }
    }
}

// ---- kernel 2: MFMA tile, single-barrier pipelined K-loop ---------------
// grid (B/128, SPLITS), block 256 = 4 waves; 128x128 tile, K=128.
__global__ __launch_bounds__(256, 2)
void tile_kernel(const ushort_t* __restrict__ e1b, const ushort_t* __restrict__ e2b,
                 const float* __restrict__ cpos, const float* __restrict__ cneg,
                 float* __restrict__ pmp, float* __restrict__ nmp, int B) {
    __shared__ __align__(16) unsigned char Bs[2][TILE_BYTES];  // 2 x 33 KB
    __shared__ float smP[128], smN[128];                       // combine scratch

    const int tid = threadIdx.x;
    const int w   = tid >> 6;
    const int l   = tid & 63;
    const int lq  = l >> 4;
    const int lm  = l & 15;
    const int row0 = blockIdx.x * 128;
    const int colSpan = B / SPLITS;                  // 1024
    const int col0 = blockIdx.y * colSpan;
    const int nTiles = colSpan / 128;                // 8

    const int wr = (w >> 1) * 64;    // wave quadrant in tile
    const int wc = (w & 1) * 64;

    // stage B tile t into buffer buf: wave w -> rows [w*32, w*32+32)
    auto stageB = [&](int t, int buf) {
        const ushort_t* g = e2b + (size_t)(col0 + t * 128 + w * 32) * DDIM + l * 8;
        unsigned char* lp = Bs[buf] + w * WAVE_SPAN;
        #pragma unroll
        for (int it = 0; it < 8; ++it)
            g2lds16(g + it * 512, lp + it * CHUNK_PITCH);
    };

    stageB(0, 0);

    // A fragments straight from global (once, L2-hit):
    // row = row0 + wr + i*16 + lm; k = k4*32 + lq*8
    short8 afr[4][4];
    {
        const ushort_t* aG = e1b + (size_t)(row0 + wr + lm) * DDIM + lq * 8;
        #pragma unroll
        for (int i = 0; i < 4; ++i)
            #pragma unroll
            for (int k4 = 0; k4 < 4; ++k4)
                afr[i][k4] = *(const short8*)(aG + i * 16 * DDIM + k4 * 32);
    }

    // fragment row R = wc + i*16 + lm; byte addr in buffer =
    //   (R>>2)*1056 + (R&3)*256 + lq*16 + kk*2   (lane-constant base)
    const int bOff = ((wc >> 2) + (lm >> 2)) * CHUNK_PITCH + (lm & 3) * 256 + lq * 16;

    float pm[4][4], nm[4][4];        // [i][r]: local row = wr + i*16 + lq*4 + r
    #pragma unroll
    for (int i = 0; i < 4; ++i)
        #pragma unroll
        for (int r = 0; r < 4; ++r) { pm[i][r] = -SENT; nm[i][r] = SENT; }

    __syncthreads();                 // drains DMA(0) (+ afr loads)

    for (int t = 0; t < nTiles; ++t) {
        // prefetch next tile into the other buffer; safe: the barrier that
        // ended iteration t-1 proves all waves finished reading it.
        if (t + 1 < nTiles) stageB(t + 1, (t + 1) & 1);

        const unsigned char* bLane = Bs[t & 1] + bOff;

        f32x4 acc[4][4];
        #pragma unroll
        for (int i = 0; i < 4; ++i)
            #pragma unroll
            for (int j = 0; j < 4; ++j)
                acc[i][j] = (f32x4){0.f, 0.f, 0.f, 0.f};

        #pragma unroll
        for (int kk = 0; kk < DDIM; kk += 32) {
            const int k4 = kk >> 5;
            const int ko = kk * 2;
            short8 bf[4];
            #pragma unroll
            for (int j = 0; j < 4; ++j)
                bf[j] = *(const short8*)(bLane + j * (4 * CHUNK_PITCH) + ko);
            #pragma unroll
            for (int i = 0; i < 4; ++i)
                #pragma unroll
                for (int j = 0; j < 4; ++j)
                    acc[i][j] = __builtin_amdgcn_mfma_f32_16x16x32_bf16(
                                    afr[i][k4], bf[j], acc[i][j], 0, 0, 0);
        }

        // branchless epilogue in dist^2 space (no sqrt; rowterm deferred)
        #pragma unroll
        for (int j = 0; j < 4; ++j) {
            int col = col0 + t * 128 + wc + j * 16 + lm;   // C/D: col = lane&15
            float cp = cpos[col];
            float cn = cneg[col];
            #pragma unroll
            for (int i = 0; i < 4; ++i)
                #pragma unroll
                for (int r = 0; r < 4; ++r) {
                    float d = acc[i][j][r];
                    pm[i][r] = fmaxf(pm[i][r], fmaf(-2.f, d, cp));
                    nm[i][r] = fminf(nm[i][r], fmaf(-2.f, d, cn));
                }
        }

        if (t + 1 < nTiles)
            __syncthreads();   // single barrier: drains DMA(t+1) (a full
                               // compute phase of slack) + readers done
    }

    // intra-wave: reduce across the 16 column-lanes
    #pragma unroll
    for (int m = 1; m < 16; m <<= 1) {
        #pragma unroll
        for (int i = 0; i < 4; ++i)
            #pragma unroll
            for (int r = 0; r < 4; ++r) {
                pm[i][r] = fmaxf(pm[i][r], __shfl_xor(pm[i][r], m, 64));
                nm[i][r] = fminf(nm[i][r], __shfl_xor(nm[i][r], m, 64));
            }
    }

    // cross-wave: waves (2h, 2h+1) share rows over complementary column
    // halves -> combine via dedicated LDS scratch.
    __syncthreads();
    if ((w & 1) == 1 && lm == 0) {
        #pragma unroll
        for (int i = 0; i < 4; ++i)
            #pragma unroll
            for (int r = 0; r < 4; ++r) {
                int lr = wr + i * 16 + lq * 4 + r;
                smP[lr] = pm[i][r];
                smN[lr] = nm[i][r];
            }
    }
    __syncthreads();
    if ((w & 1) == 0 && lm == 0) {
        #pragma unroll
        for (int i = 0; i < 4; ++i)
            #pragma unroll
            for (int r = 0; r < 4; ++r) {
                int lr  = wr + i * 16 + lq * 4 + r;     // C/D: row = quad*4+reg
                int row = row0 + lr;
                pmp[(size_t)blockIdx.y * B + row] = fmaxf(pm[i][r], smP[lr]);
                nmp[(size_t)blockIdx.y * B + row] = fminf(nm[i][r], smN[lr]);
            }
    }
}

// ---- kernel 3: per-row combine + hinge; atomic partials; last block divides ----
__global__ void reduce_kernel(const float* __restrict__ pmp, const float* __restrict__ nmp,
                              const float* __restrict__ rowterm, const int* __restrict__ target,
                              float* __restrict__ redsum, int* __restrict__ ticket,
                              float* __restrict__ out, int B) {
    int row = blockIdx.x * blockDim.x + threadIdx.x;    // 32 x 256 = 8192
    float s = 0.f, c = 0.f;
    {
        float pmv = -SENT, nmv = SENT;
        #pragma unroll
        for (int sp = 0; sp < SPLITS; ++sp) {
            pmv = fmaxf(pmv, pmp[(size_t)sp * B + row]);
            nmv = fminf(nmv, nmp[(size_t)sp * B + row]);
        }
        float rt = rowterm[row];
        float dp = sqrtf(fmaxf(rt + pmv, 0.f));
        float dn = sqrtf(fmaxf(rt + nmv, 0.f));
        if (target[row] == 1) {
            s = fmaxf(dp - dn + MARGIN, 0.f);
            c = 1.f;
        }
    }
    #pragma unroll
    for (int off = 32; off > 0; off >>= 1) {
        s += __shfl_down(s, off, 64);
        c += __shfl_down(c, off, 64);
    }
    __shared__ float ls[4], lc[4];
    int wv = threadIdx.x >> 6, ln = threadIdx.x & 63;
    if (ln == 0) { ls[wv] = s; lc[wv] = c; }
    __syncthreads();
    if (threadIdx.x == 0) {
        float ss = ls[0] + ls[1] + ls[2] + ls[3];
        float cc = lc[0] + lc[1] + lc[2] + lc[3];
        atomicAdd(&redsum[0], ss);
        atomicAdd(&redsum[1], cc);
        __threadfence();
        int done = atomicAdd(ticket, 1);
        if (done == (int)gridDim.x - 1) {
            __threadfence();
            float fs = __hip_atomic_load(&redsum[0], __ATOMIC_RELAXED, __HIP_MEMORY_SCOPE_AGENT);
            float fc = __hip_atomic_load(&redsum[1], __ATOMIC_RELAXED, __HIP_MEMORY_SCOPE_AGENT);
            out[0] = fs / fc;
        }
    }
}

extern "C" void kernel_launch(void* const* d_in, const int* in_sizes, int n_in,
                              void* d_out, int out_size, void* d_ws, size_t ws_size,
                              hipStream_t stream) {
    const float* e1     = (const float*)d_in[0];
    const float* e2     = (const float*)d_in[1];
    const int*   target = (const int*)d_in[2];
    float* out = (float*)d_out;
    const int B = in_sizes[2];                       // 8192

    // ws layout: e1b | e2b | rowterm | cpos | cneg | pmp | nmp | redsum | ticket (~4.8 MB)
    char* p = (char*)d_ws;
    ushort_t* e1b  = (ushort_t*)p;   p += (size_t)B * DDIM * 2;   // 2 MB
    ushort_t* e2b  = (ushort_t*)p;   p += (size_t)B * DDIM * 2;   // 2 MB
    float* rowterm = (float*)p;      p += (size_t)B * 4;
    float* cpos    = (float*)p;      p += (size_t)B * 4;
    float* cneg    = (float*)p;      p += (size_t)B * 4;
    float* pmp     = (float*)p;      p += (size_t)SPLITS * B * 4;
    float* nmp     = (float*)p;      p += (size_t)SPLITS * B * 4;
    float* redsum  = (float*)p;      p += 2 * 4;
    int*   ticket  = (int*)p;

    {   // prep: one wave per row, 2B rows, 4 waves/block
        int blocks = (2 * B + 3) / 4;
        prep_kernel<<<blocks, 256, 0, stream>>>(e1, e2, target, e1b, e2b,
                                                rowterm, cpos, cneg, redsum, ticket, B);
    }
    {   // 64 row-blocks x 8 col-splits = 512 blocks = 2/CU (~68.6 KB LDS)
        dim3 grid(B / 128, SPLITS);
        tile_kernel<<<grid, 256, 0, stream>>>(e1b, e2b, cpos, cneg, pmp, nmp, B);
    }
    reduce_kernel<<<32, 256, 0, stream>>>(pmp, nmp, rowterm, target,
                                          redsum, ticket, out, B);
}